// Round 1
// baseline (1264.492 us; speedup 1.0000x reference)
//
#include <hip/hip_runtime.h>

// SparseAffinity_Propagate: CSPN-style 8-neighbor propagation, 24 iterations.
// B=8, H=W=768. Offsets (dy,dx): (-5,0)(-1,0)(0,5)(0,1)(5,0)(1,0)(0,-5)(0,-1)
//
// Fusion: result = sum_c (A*w_c) * prev[p+off_c] + Bias
//   w_c  = guidance[c] shifted by off_c, normalized by sum|.| (clipped 1e-6)
//   A    = 1 - m, m = sign(sparse_depth)  (0 or 1 here)
//   Bias = (A*(1-gs) + m) * blur_depth,  gs = sum_c w_c
// Sparse pixels get all-zero weights and Bias = raw -> stay fixed. Exactly
// matches the reference's per-iteration residual + sparse blend.

#define HH 768
#define WW 768
#define BATCH 8
#define PLANE (HH * WW)           // 589824
#define TOTAL (BATCH * PLANE)     // 4718592
#define NITER 24

#define DYS {-5, -1, 0, 0, 5, 1, 0, 0}
#define DXS {0, 0, 5, 1, 0, 0, -5, -1}

// ---------------------------------------------------------------------------
// Precompute pre-scaled weights (8 planar channels of size TOTAL) + bias.
// ---------------------------------------------------------------------------
__global__ __launch_bounds__(256) void precompute_kernel(
    const float* __restrict__ g,       // (B,8,H,W)
    const float* __restrict__ blur,    // (B,1,H,W)
    const float* __restrict__ sparse,  // (B,1,H,W)
    float* __restrict__ wout,          // (8, B*H*W)  A-scaled weights
    float* __restrict__ bias)          // (B*H*W)
{
    const int dy[8] = DYS;
    const int dx[8] = DXS;
    int x = blockIdx.x * blockDim.x + threadIdx.x;
    int y = blockIdx.y;
    int b = blockIdx.z;
    if (x >= WW) return;

    const float* gb = g + (size_t)b * 8 * PLANE;
    float w[8];
    float abssum = 0.f;
#pragma unroll
    for (int c = 0; c < 8; ++c) {
        int yy = y + dy[c];
        int xx = x + dx[c];
        float v = 0.f;
        if (yy >= 0 && yy < HH && xx >= 0 && xx < WW)
            v = gb[c * PLANE + yy * WW + xx];
        w[c] = v;
        abssum += fabsf(v);
    }
    float inv = 1.f / fmaxf(abssum, 1e-6f);
    float gs = 0.f;
#pragma unroll
    for (int c = 0; c < 8; ++c) {
        w[c] *= inv;
        gs += w[c];
    }

    int pidx = b * PLANE + y * WW + x;
    float sd = sparse[pidx];
    float m = (sd > 0.f) ? 1.f : ((sd < 0.f) ? -1.f : 0.f);
    float A = 1.f - m;
    float raw = blur[pidx];
    float bc = (A * (1.f - gs) + m) * raw;

#pragma unroll
    for (int c = 0; c < 8; ++c)
        wout[c * TOTAL + pidx] = A * w[c];
    bias[pidx] = bc;
}

// ---------------------------------------------------------------------------
// One propagation step: out = sum_c w_c * prev[p+off_c] + bias
// ---------------------------------------------------------------------------
__global__ __launch_bounds__(256) void step_kernel(
    const float* __restrict__ w,     // (8, B*H*W)
    const float* __restrict__ bias,  // (B*H*W)
    const float* __restrict__ prev,  // (B,H,W)
    float* __restrict__ next)        // (B,H,W)
{
    const int dy[8] = DYS;
    const int dx[8] = DXS;
    int x = blockIdx.x * blockDim.x + threadIdx.x;
    int y = blockIdx.y;
    int b = blockIdx.z;
    if (x >= WW) return;

    int pidx = b * PLANE + y * WW + x;
    const float* pb = prev + b * PLANE;

    float acc = bias[pidx];
#pragma unroll
    for (int c = 0; c < 8; ++c) {
        int yy = y + dy[c];
        int xx = x + dx[c];
        float n = 0.f;
        if (yy >= 0 && yy < HH && xx >= 0 && xx < WW)
            n = pb[yy * WW + xx];
        acc = fmaf(w[c * TOTAL + pidx], n, acc);
    }
    next[pidx] = acc;
}

// ---------------------------------------------------------------------------
// Fallback step (small ws): recompute weights/bias from inputs every step.
// ---------------------------------------------------------------------------
__global__ __launch_bounds__(256) void step_recompute_kernel(
    const float* __restrict__ g,
    const float* __restrict__ blur,
    const float* __restrict__ sparse,
    const float* __restrict__ prev,
    float* __restrict__ next)
{
    const int dy[8] = DYS;
    const int dx[8] = DXS;
    int x = blockIdx.x * blockDim.x + threadIdx.x;
    int y = blockIdx.y;
    int b = blockIdx.z;
    if (x >= WW) return;

    const float* gb = g + (size_t)b * 8 * PLANE;
    float w[8];
    float abssum = 0.f;
#pragma unroll
    for (int c = 0; c < 8; ++c) {
        int yy = y + dy[c];
        int xx = x + dx[c];
        float v = 0.f;
        if (yy >= 0 && yy < HH && xx >= 0 && xx < WW)
            v = gb[c * PLANE + yy * WW + xx];
        w[c] = v;
        abssum += fabsf(v);
    }
    float inv = 1.f / fmaxf(abssum, 1e-6f);
    float gs = 0.f;
#pragma unroll
    for (int c = 0; c < 8; ++c) {
        w[c] *= inv;
        gs += w[c];
    }
    int pidx = b * PLANE + y * WW + x;
    float sd = sparse[pidx];
    float m = (sd > 0.f) ? 1.f : ((sd < 0.f) ? -1.f : 0.f);
    float A = 1.f - m;
    float raw = blur[pidx];

    const float* pb = prev + b * PLANE;
    float acc = 0.f;
#pragma unroll
    for (int c = 0; c < 8; ++c) {
        int yy = y + dy[c];
        int xx = x + dx[c];
        float n = 0.f;
        if (yy >= 0 && yy < HH && xx >= 0 && xx < WW)
            n = pb[yy * WW + xx];
        acc = fmaf(A * w[c], n, acc);
    }
    next[pidx] = acc + (A * (1.f - gs) + m) * raw;
}

// ---------------------------------------------------------------------------
extern "C" void kernel_launch(void* const* d_in, const int* in_sizes, int n_in,
                              void* d_out, int out_size, void* d_ws, size_t ws_size,
                              hipStream_t stream) {
    const float* g      = (const float*)d_in[0];  // guidance (B,8,H,W)
    const float* blur   = (const float*)d_in[1];  // blur_depth (B,1,H,W)
    const float* sparse = (const float*)d_in[2];  // sparse_depth (B,1,H,W)
    float* out = (float*)d_out;

    dim3 block(256, 1, 1);
    dim3 grid(WW / 256, HH, BATCH);  // 3 x 768 x 8

    const size_t need_fast = ((size_t)8 * TOTAL + TOTAL + TOTAL) * sizeof(float);

    if (ws_size >= need_fast) {
        float* w    = (float*)d_ws;        // 8*TOTAL
        float* bias = w + (size_t)8 * TOTAL;
        float* r0   = bias + TOTAL;

        precompute_kernel<<<grid, block, 0, stream>>>(g, blur, sparse, w, bias);

        const float* prev = blur;
        for (int it = 0; it < NITER; ++it) {
            float* nxt = (it % 2 == 0) ? r0 : out;  // it=23 -> out
            step_kernel<<<grid, block, 0, stream>>>(w, bias, prev, nxt);
            prev = nxt;
        }
    } else {
        // Fallback: only one ping buffer in ws; recompute weights each step.
        float* r0 = (float*)d_ws;
        const float* prev = blur;
        for (int it = 0; it < NITER; ++it) {
            float* nxt = (it % 2 == 0) ? r0 : out;
            step_recompute_kernel<<<grid, block, 0, stream>>>(g, blur, sparse,
                                                              prev, nxt);
            prev = nxt;
        }
    }
}

// Round 2
// 959.187 us; speedup vs baseline: 1.3183x; 1.3183x over previous
//
#include <hip/hip_runtime.h>

// SparseAffinity_Propagate: CSPN-style 8-neighbor propagation, 24 iterations.
// B=8, H=W=768. Offsets (dy,dx): (-5,0)(-1,0)(0,5)(0,1)(5,0)(1,0)(0,-5)(0,-1)
//
// Fusion: result = sum_c (A*w_c) * prev[p+off_c] + Bias  (see Round 0 notes)
// Round 1: weights stored as 8 x fp16 AoS (16 B/pixel, one dwordx4 load),
// bias fp32. Cuts per-step traffic 44 -> 28 B/px; weights bounded in [-1,1]
// so fp16 rel err ~4.9e-4 -> predicted absmax ~1-3e-2 < 4.66e-2 threshold.

#define HH 768
#define WW 768
#define BATCH 8
#define PLANE (HH * WW)           // 589824
#define TOTAL (BATCH * PLANE)     // 4718592
#define NITER 24

#define DYS {-5, -1, 0, 0, 5, 1, 0, 0}
#define DXS {0, 0, 5, 1, 0, 0, -5, -1}

typedef _Float16 half8 __attribute__((ext_vector_type(8)));

// ---------------------------------------------------------------------------
// Precompute pre-scaled weights (fp16 AoS, 16 B/px) + fp32 bias.
// ---------------------------------------------------------------------------
__global__ __launch_bounds__(256) void precompute_kernel(
    const float* __restrict__ g,       // (B,8,H,W)
    const float* __restrict__ blur,    // (B,1,H,W)
    const float* __restrict__ sparse,  // (B,1,H,W)
    half8* __restrict__ wout,          // (B*H*W) x 8 fp16  (AoS)
    float* __restrict__ bias)          // (B*H*W)
{
    const int dy[8] = DYS;
    const int dx[8] = DXS;
    int x = blockIdx.x * blockDim.x + threadIdx.x;
    int y = blockIdx.y;
    int b = blockIdx.z;
    if (x >= WW) return;

    const float* gb = g + (size_t)b * 8 * PLANE;
    float w[8];
    float abssum = 0.f;
#pragma unroll
    for (int c = 0; c < 8; ++c) {
        int yy = y + dy[c];
        int xx = x + dx[c];
        float v = 0.f;
        if (yy >= 0 && yy < HH && xx >= 0 && xx < WW)
            v = gb[c * PLANE + yy * WW + xx];
        w[c] = v;
        abssum += fabsf(v);
    }
    float inv = 1.f / fmaxf(abssum, 1e-6f);
    float gs = 0.f;
#pragma unroll
    for (int c = 0; c < 8; ++c) {
        w[c] *= inv;
        gs += w[c];
    }

    int pidx = b * PLANE + y * WW + x;
    float sd = sparse[pidx];
    float m = (sd > 0.f) ? 1.f : ((sd < 0.f) ? -1.f : 0.f);
    float A = 1.f - m;
    float raw = blur[pidx];
    float bc = (A * (1.f - gs) + m) * raw;

    half8 hv;
#pragma unroll
    for (int c = 0; c < 8; ++c)
        hv[c] = (_Float16)(A * w[c]);
    wout[pidx] = hv;
    bias[pidx] = bc;
}

// ---------------------------------------------------------------------------
// One propagation step: out = sum_c w_c * prev[p+off_c] + bias
// ---------------------------------------------------------------------------
__global__ __launch_bounds__(256) void step_kernel(
    const half8* __restrict__ w,     // (B*H*W) x 8 fp16
    const float* __restrict__ bias,  // (B*H*W)
    const float* __restrict__ prev,  // (B,H,W)
    float* __restrict__ next)        // (B,H,W)
{
    const int dy[8] = DYS;
    const int dx[8] = DXS;
    int x = blockIdx.x * blockDim.x + threadIdx.x;
    int y = blockIdx.y;
    int b = blockIdx.z;
    if (x >= WW) return;

    int pidx = b * PLANE + y * WW + x;
    const float* pb = prev + b * PLANE;

    half8 hv = w[pidx];
    float acc = bias[pidx];
#pragma unroll
    for (int c = 0; c < 8; ++c) {
        int yy = y + dy[c];
        int xx = x + dx[c];
        float n = 0.f;
        if (yy >= 0 && yy < HH && xx >= 0 && xx < WW)
            n = pb[yy * WW + xx];
        acc = fmaf((float)hv[c], n, acc);
    }
    next[pidx] = acc;
}

// ---------------------------------------------------------------------------
// Fallback step (small ws): recompute weights/bias from inputs every step.
// ---------------------------------------------------------------------------
__global__ __launch_bounds__(256) void step_recompute_kernel(
    const float* __restrict__ g,
    const float* __restrict__ blur,
    const float* __restrict__ sparse,
    const float* __restrict__ prev,
    float* __restrict__ next)
{
    const int dy[8] = DYS;
    const int dx[8] = DXS;
    int x = blockIdx.x * blockDim.x + threadIdx.x;
    int y = blockIdx.y;
    int b = blockIdx.z;
    if (x >= WW) return;

    const float* gb = g + (size_t)b * 8 * PLANE;
    float w[8];
    float abssum = 0.f;
#pragma unroll
    for (int c = 0; c < 8; ++c) {
        int yy = y + dy[c];
        int xx = x + dx[c];
        float v = 0.f;
        if (yy >= 0 && yy < HH && xx >= 0 && xx < WW)
            v = gb[c * PLANE + yy * WW + xx];
        w[c] = v;
        abssum += fabsf(v);
    }
    float inv = 1.f / fmaxf(abssum, 1e-6f);
    float gs = 0.f;
#pragma unroll
    for (int c = 0; c < 8; ++c) {
        w[c] *= inv;
        gs += w[c];
    }
    int pidx = b * PLANE + y * WW + x;
    float sd = sparse[pidx];
    float m = (sd > 0.f) ? 1.f : ((sd < 0.f) ? -1.f : 0.f);
    float A = 1.f - m;
    float raw = blur[pidx];

    const float* pb = prev + b * PLANE;
    float acc = 0.f;
#pragma unroll
    for (int c = 0; c < 8; ++c) {
        int yy = y + dy[c];
        int xx = x + dx[c];
        float n = 0.f;
        if (yy >= 0 && yy < HH && xx >= 0 && xx < WW)
            n = pb[yy * WW + xx];
        acc = fmaf(A * w[c], n, acc);
    }
    next[pidx] = acc + (A * (1.f - gs) + m) * raw;
}

// ---------------------------------------------------------------------------
extern "C" void kernel_launch(void* const* d_in, const int* in_sizes, int n_in,
                              void* d_out, int out_size, void* d_ws, size_t ws_size,
                              hipStream_t stream) {
    const float* g      = (const float*)d_in[0];  // guidance (B,8,H,W)
    const float* blur   = (const float*)d_in[1];  // blur_depth (B,1,H,W)
    const float* sparse = (const float*)d_in[2];  // sparse_depth (B,1,H,W)
    float* out = (float*)d_out;

    dim3 block(256, 1, 1);
    dim3 grid(WW / 256, HH, BATCH);  // 3 x 768 x 8

    // fast path: fp16 AoS weights (16 B/px) + fp32 bias + ping buffer
    const size_t need_fast = (size_t)TOTAL * 16 + (size_t)TOTAL * 4 * 2;

    if (ws_size >= need_fast) {
        half8* w    = (half8*)d_ws;                       // TOTAL x 16 B
        float* bias = (float*)((char*)d_ws + (size_t)TOTAL * 16);
        float* r0   = bias + TOTAL;

        precompute_kernel<<<grid, block, 0, stream>>>(g, blur, sparse, w, bias);

        const float* prev = blur;
        for (int it = 0; it < NITER; ++it) {
            float* nxt = (it % 2 == 0) ? r0 : out;  // it=23 -> out
            step_kernel<<<grid, block, 0, stream>>>(w, bias, prev, nxt);
            prev = nxt;
        }
    } else {
        // Fallback: only one ping buffer in ws; recompute weights each step.
        float* r0 = (float*)d_ws;
        const float* prev = blur;
        for (int it = 0; it < NITER; ++it) {
            float* nxt = (it % 2 == 0) ? r0 : out;
            step_recompute_kernel<<<grid, block, 0, stream>>>(g, blur, sparse,
                                                              prev, nxt);
            prev = nxt;
        }
    }
}

// Round 3
// 952.948 us; speedup vs baseline: 1.3269x; 1.0065x over previous
//
#include <hip/hip_runtime.h>

// SparseAffinity_Propagate: CSPN-style 8-neighbor propagation, 24 iterations.
// B=8, H=W=768. Offsets (dy,dx): (-5,0)(-1,0)(0,5)(0,1)(5,0)(1,0)(0,-5)(0,-1)
//
// Fusion (R0): result = sum_c (A*w_c) * prev[p+off_c] + Bias
// R1: weights fp16 AoS (16 B/px), bias fp32 -> 28 B/px per step.
// R2: 4 px/thread, all vmem as aligned 16B vectors (15 insts/4px vs 44)
//     -> attacks vmem request-rate bound (VALUBusy was 13%, bytes at 3.6 TB/s
//        effective despite L3-resident working set).

#define HH 768
#define WW 768
#define BATCH 8
#define PLANE (HH * WW)           // 589824
#define TOTAL (BATCH * PLANE)     // 4718592
#define NITER 24

#define DYS {-5, -1, 0, 0, 5, 1, 0, 0}
#define DXS {0, 0, 5, 1, 0, 0, -5, -1}

typedef _Float16 half8 __attribute__((ext_vector_type(8)));
typedef float f4 __attribute__((ext_vector_type(4)));

__device__ __forceinline__ f4 ldf4(const float* p) { return *(const f4*)p; }

// ---------------------------------------------------------------------------
// Precompute pre-scaled weights (fp16 AoS, 16 B/px) + fp32 bias.
// Block = 192 threads = one row (4 px/thread). Grid (1, 768, 8).
// ---------------------------------------------------------------------------
__global__ __launch_bounds__(192) void precompute_kernel(
    const float* __restrict__ g,       // (B,8,H,W)
    const float* __restrict__ blur,    // (B,1,H,W)
    const float* __restrict__ sparse,  // (B,1,H,W)
    half8* __restrict__ wout,          // (B*H*W) x 8 fp16  (AoS)
    float* __restrict__ bias)          // (B*H*W)
{
    const int x0 = 4 * threadIdx.x;
    const int y  = blockIdx.y;
    const int b  = blockIdx.z;
    const float* gb = g + (size_t)b * 8 * PLANE;
    const int rowb = y * WW;
    const int pidx = b * PLANE + rowb + x0;

    f4 wv[8];
    if (x0 >= 8 && x0 <= 756) {
        const f4 zero = (f4)0.f;
        // dy planes (aligned, row-guarded; guards are block-uniform)
        wv[0] = (y >= 5)      ? ldf4(gb + 0 * PLANE + (y - 5) * WW + x0) : zero;
        wv[1] = (y >= 1)      ? ldf4(gb + 1 * PLANE + (y - 1) * WW + x0) : zero;
        wv[4] = (y <= HH - 6) ? ldf4(gb + 4 * PLANE + (y + 5) * WW + x0) : zero;
        wv[5] = (y <= HH - 2) ? ldf4(gb + 5 * PLANE + (y + 1) * WW + x0) : zero;
        // dx planes: two aligned f4 loads each, component-select the shift
        {   // c=2, dx=+5 -> x0+5..x0+8
            f4 a = ldf4(gb + 2 * PLANE + rowb + x0 + 4);
            f4 bq = ldf4(gb + 2 * PLANE + rowb + x0 + 8);
            wv[2] = f4{a[1], a[2], a[3], bq[0]};
        }
        {   // c=3, dx=+1 -> x0+1..x0+4
            f4 a = ldf4(gb + 3 * PLANE + rowb + x0);
            f4 bq = ldf4(gb + 3 * PLANE + rowb + x0 + 4);
            wv[3] = f4{a[1], a[2], a[3], bq[0]};
        }
        {   // c=6, dx=-5 -> x0-5..x0-2
            f4 a = ldf4(gb + 6 * PLANE + rowb + x0 - 8);
            f4 bq = ldf4(gb + 6 * PLANE + rowb + x0 - 4);
            wv[6] = f4{a[3], bq[0], bq[1], bq[2]};
        }
        {   // c=7, dx=-1 -> x0-1..x0+2
            f4 a = ldf4(gb + 7 * PLANE + rowb + x0 - 4);
            f4 bq = ldf4(gb + 7 * PLANE + rowb + x0);
            wv[7] = f4{a[3], bq[0], bq[1], bq[2]};
        }
    } else {
        // Edge threads: guarded scalar gathers
        const int dy[8] = DYS;
        const int dx[8] = DXS;
#pragma unroll
        for (int c = 0; c < 8; ++c) {
#pragma unroll
            for (int j = 0; j < 4; ++j) {
                int yy = y + dy[c];
                int xx = x0 + j + dx[c];
                float v = 0.f;
                if (yy >= 0 && yy < HH && xx >= 0 && xx < WW)
                    v = gb[c * PLANE + yy * WW + xx];
                wv[c][j] = v;
            }
        }
    }

    f4 raw = ldf4(blur + pidx);
    f4 sd  = ldf4(sparse + pidx);
    f4 bout;
#pragma unroll
    for (int j = 0; j < 4; ++j) {
        float abssum = 0.f;
#pragma unroll
        for (int c = 0; c < 8; ++c) abssum += fabsf(wv[c][j]);
        float inv = 1.f / fmaxf(abssum, 1e-6f);
        float gs = 0.f;
#pragma unroll
        for (int c = 0; c < 8; ++c) gs += wv[c][j] * inv;
        float s = sd[j];
        float m = (s > 0.f) ? 1.f : ((s < 0.f) ? -1.f : 0.f);
        float A = 1.f - m;
        bout[j] = (A * (1.f - gs) + m) * raw[j];
        float Ai = A * inv;
        half8 hv;
#pragma unroll
        for (int c = 0; c < 8; ++c) hv[c] = (_Float16)(Ai * wv[c][j]);
        wout[pidx + j] = hv;
    }
    *(f4*)(bias + pidx) = bout;
}

// ---------------------------------------------------------------------------
// One propagation step: out = sum_c w_c * prev[p+off_c] + bias
// Block = 192 threads = one row (4 px/thread). Grid (1, 768, 8).
// ---------------------------------------------------------------------------
__global__ __launch_bounds__(192) void step_kernel(
    const half8* __restrict__ w,     // (B*H*W) x 8 fp16
    const float* __restrict__ bias,  // (B*H*W)
    const float* __restrict__ prev,  // (B,H,W)
    float* __restrict__ next)        // (B,H,W)
{
    const int x0 = 4 * threadIdx.x;
    const int y  = blockIdx.y;
    const int b  = blockIdx.z;
    const int rowb = y * WW;
    const int pidx = b * PLANE + rowb + x0;
    const float* pb = prev + b * PLANE;

    half8 hv0 = w[pidx + 0];
    half8 hv1 = w[pidx + 1];
    half8 hv2 = w[pidx + 2];
    half8 hv3 = w[pidx + 3];
    f4 acc = ldf4(bias + pidx);

    if (x0 >= 8 && x0 <= 756) {
        const f4 zero = (f4)0.f;
        // dy taps (aligned, block-uniform guards)
        f4 um5 = (y >= 5)      ? ldf4(pb + (y - 5) * WW + x0) : zero;
        f4 um1 = (y >= 1)      ? ldf4(pb + (y - 1) * WW + x0) : zero;
        f4 dp5 = (y <= HH - 6) ? ldf4(pb + (y + 5) * WW + x0) : zero;
        f4 dp1 = (y <= HH - 2) ? ldf4(pb + (y + 1) * WW + x0) : zero;
        // row y: 5 aligned f4 covering [x0-8, x0+11]
        f4 m2 = ldf4(pb + rowb + x0 - 8);
        f4 m1 = ldf4(pb + rowb + x0 - 4);
        f4 c0 = ldf4(pb + rowb + x0);
        f4 p1 = ldf4(pb + rowb + x0 + 4);
        f4 p2 = ldf4(pb + rowb + x0 + 8);
        f4 tm5 = f4{m2[3], m1[0], m1[1], m1[2]};   // dx=-5
        f4 tm1 = f4{m1[3], c0[0], c0[1], c0[2]};   // dx=-1
        f4 tp1 = f4{c0[1], c0[2], c0[3], p1[0]};   // dx=+1
        f4 tp5 = f4{p1[1], p1[2], p1[3], p2[0]};   // dx=+5

        // c order: 0:(-5,0) 1:(-1,0) 2:(0,+5) 3:(0,+1) 4:(+5,0) 5:(+1,0) 6:(0,-5) 7:(0,-1)
        acc[0] = fmaf((float)hv0[0], um5[0], acc[0]);
        acc[1] = fmaf((float)hv1[0], um5[1], acc[1]);
        acc[2] = fmaf((float)hv2[0], um5[2], acc[2]);
        acc[3] = fmaf((float)hv3[0], um5[3], acc[3]);

        acc[0] = fmaf((float)hv0[1], um1[0], acc[0]);
        acc[1] = fmaf((float)hv1[1], um1[1], acc[1]);
        acc[2] = fmaf((float)hv2[1], um1[2], acc[2]);
        acc[3] = fmaf((float)hv3[1], um1[3], acc[3]);

        acc[0] = fmaf((float)hv0[2], tp5[0], acc[0]);
        acc[1] = fmaf((float)hv1[2], tp5[1], acc[1]);
        acc[2] = fmaf((float)hv2[2], tp5[2], acc[2]);
        acc[3] = fmaf((float)hv3[2], tp5[3], acc[3]);

        acc[0] = fmaf((float)hv0[3], tp1[0], acc[0]);
        acc[1] = fmaf((float)hv1[3], tp1[1], acc[1]);
        acc[2] = fmaf((float)hv2[3], tp1[2], acc[2]);
        acc[3] = fmaf((float)hv3[3], tp1[3], acc[3]);

        acc[0] = fmaf((float)hv0[4], dp5[0], acc[0]);
        acc[1] = fmaf((float)hv1[4], dp5[1], acc[1]);
        acc[2] = fmaf((float)hv2[4], dp5[2], acc[2]);
        acc[3] = fmaf((float)hv3[4], dp5[3], acc[3]);

        acc[0] = fmaf((float)hv0[5], dp1[0], acc[0]);
        acc[1] = fmaf((float)hv1[5], dp1[1], acc[1]);
        acc[2] = fmaf((float)hv2[5], dp1[2], acc[2]);
        acc[3] = fmaf((float)hv3[5], dp1[3], acc[3]);

        acc[0] = fmaf((float)hv0[6], tm5[0], acc[0]);
        acc[1] = fmaf((float)hv1[6], tm5[1], acc[1]);
        acc[2] = fmaf((float)hv2[6], tm5[2], acc[2]);
        acc[3] = fmaf((float)hv3[6], tm5[3], acc[3]);

        acc[0] = fmaf((float)hv0[7], tm1[0], acc[0]);
        acc[1] = fmaf((float)hv1[7], tm1[1], acc[1]);
        acc[2] = fmaf((float)hv2[7], tm1[2], acc[2]);
        acc[3] = fmaf((float)hv3[7], tm1[3], acc[3]);
    } else {
        const int dy[8] = DYS;
        const int dx[8] = DXS;
        half8 hvs[4] = {hv0, hv1, hv2, hv3};
#pragma unroll
        for (int j = 0; j < 4; ++j) {
#pragma unroll
            for (int c = 0; c < 8; ++c) {
                int yy = y + dy[c];
                int xx = x0 + j + dx[c];
                float n = 0.f;
                if (yy >= 0 && yy < HH && xx >= 0 && xx < WW)
                    n = pb[yy * WW + xx];
                acc[j] = fmaf((float)hvs[j][c], n, acc[j]);
            }
        }
    }
    *(f4*)(next + pidx) = acc;
}

// ---------------------------------------------------------------------------
// Fallback step (small ws): recompute weights/bias from inputs every step.
// ---------------------------------------------------------------------------
__global__ __launch_bounds__(256) void step_recompute_kernel(
    const float* __restrict__ g,
    const float* __restrict__ blur,
    const float* __restrict__ sparse,
    const float* __restrict__ prev,
    float* __restrict__ next)
{
    const int dy[8] = DYS;
    const int dx[8] = DXS;
    int x = blockIdx.x * blockDim.x + threadIdx.x;
    int y = blockIdx.y;
    int b = blockIdx.z;
    if (x >= WW) return;

    const float* gb = g + (size_t)b * 8 * PLANE;
    float w[8];
    float abssum = 0.f;
#pragma unroll
    for (int c = 0; c < 8; ++c) {
        int yy = y + dy[c];
        int xx = x + dx[c];
        float v = 0.f;
        if (yy >= 0 && yy < HH && xx >= 0 && xx < WW)
            v = gb[c * PLANE + yy * WW + xx];
        w[c] = v;
        abssum += fabsf(v);
    }
    float inv = 1.f / fmaxf(abssum, 1e-6f);
    float gs = 0.f;
#pragma unroll
    for (int c = 0; c < 8; ++c) {
        w[c] *= inv;
        gs += w[c];
    }
    int pidx = b * PLANE + y * WW + x;
    float sd = sparse[pidx];
    float m = (sd > 0.f) ? 1.f : ((sd < 0.f) ? -1.f : 0.f);
    float A = 1.f - m;
    float raw = blur[pidx];

    const float* pb = prev + b * PLANE;
    float acc = 0.f;
#pragma unroll
    for (int c = 0; c < 8; ++c) {
        int yy = y + dy[c];
        int xx = x + dx[c];
        float n = 0.f;
        if (yy >= 0 && yy < HH && xx >= 0 && xx < WW)
            n = pb[yy * WW + xx];
        acc = fmaf(A * w[c], n, acc);
    }
    next[pidx] = acc + (A * (1.f - gs) + m) * raw;
}

// ---------------------------------------------------------------------------
extern "C" void kernel_launch(void* const* d_in, const int* in_sizes, int n_in,
                              void* d_out, int out_size, void* d_ws, size_t ws_size,
                              hipStream_t stream) {
    const float* g      = (const float*)d_in[0];  // guidance (B,8,H,W)
    const float* blur   = (const float*)d_in[1];  // blur_depth (B,1,H,W)
    const float* sparse = (const float*)d_in[2];  // sparse_depth (B,1,H,W)
    float* out = (float*)d_out;

    dim3 block(192, 1, 1);           // one row, 4 px/thread
    dim3 grid(1, HH, BATCH);         // 1 x 768 x 8

    // fast path: fp16 AoS weights (16 B/px) + fp32 bias + ping buffer
    const size_t need_fast = (size_t)TOTAL * 16 + (size_t)TOTAL * 4 * 2;

    if (ws_size >= need_fast) {
        half8* w    = (half8*)d_ws;                       // TOTAL x 16 B
        float* bias = (float*)((char*)d_ws + (size_t)TOTAL * 16);
        float* r0   = bias + TOTAL;

        precompute_kernel<<<grid, block, 0, stream>>>(g, blur, sparse, w, bias);

        const float* prev = blur;
        for (int it = 0; it < NITER; ++it) {
            float* nxt = (it % 2 == 0) ? r0 : out;  // it=23 -> out
            step_kernel<<<grid, block, 0, stream>>>(w, bias, prev, nxt);
            prev = nxt;
        }
    } else {
        // Fallback: only one ping buffer in ws; recompute weights each step.
        dim3 block2(256, 1, 1);
        dim3 grid2(WW / 256, HH, BATCH);
        float* r0 = (float*)d_ws;
        const float* prev = blur;
        for (int it = 0; it < NITER; ++it) {
            float* nxt = (it % 2 == 0) ? r0 : out;
            step_recompute_kernel<<<grid2, block2, 0, stream>>>(g, blur, sparse,
                                                                prev, nxt);
            prev = nxt;
        }
    }
}